// Round 16
// baseline (109.192 us; speedup 1.0000x reference)
//
#include <hip/hip_runtime.h>
#include <hip/hip_fp16.h>

#define BB 16
#define HH 512
#define ROWLEN 1536   // W*C
#define KK 51
#define RR 25
typedef unsigned long long u64;
typedef float nt4 __attribute__((ext_vector_type(4)));   // native vec for NT ld/st

// chunk-level XOR swizzle (involution): spreads strided chunk patterns over
// all 8 bank groups; bijective (only low 3 bits change).
__device__ __forceinline__ int sq(int q) { return q ^ ((q >> 3) & 7); }

// ---------------- K0: reduce 2D kernel to 1D weights (g[i] = row sum) -------
__global__ void k_weights(const float* __restrict__ k2d, float* __restrict__ g,
                          __half2* __restrict__ g2) {
    int i = threadIdx.x;
    if (i < KK) {
        float s = 0.f;
        for (int j = 0; j < KK; ++j) s += k2d[i * KK + j];
        g[i] = s;
        g2[i] = __float2half2_rn(s);
    }
}

// ---------------- H-pass: 51-tap conv along w, row-pair packed fp16 ---------
// 4 rows/block, 256 threads = 2 row-pairs x 128 lanes. half2 lanes carry the
// two rows of a pair. Plane = (rowpair, channel), e = w+28, chunk-swizzled.
// Thread: 4 px x 3 ch x 2 rows = 24 outputs, 612 hfma2, guard compile-time.
// MASKP=false: src = f32 img (nontemporal), also emits imgh.
// MASKP=true:  src = bit-packed mask (1 bit/px, 48 words/row).
#define PSTR 576     // half2 per plane = 144 chunks (multiple of 8)
template<bool MASKP>
__global__ __launch_bounds__(256, 4) void k_hconv(const void* __restrict__ srcv,
                                                  __half* __restrict__ dst,
                                                  __half* __restrict__ imgh,
                                                  const __half2* __restrict__ g2src) {
    __shared__ __align__(16) __half2 pl[6 * PSTR];
    const int t = threadIdx.x;
    const int row0 = blockIdx.x * 4;             // first of 4 rows (b*512+h)

    __half2 gw2[KK];
    #pragma unroll
    for (int i = 0; i < KK; ++i) gw2[i] = g2src[i];   // uniform

    const int rp = t >> 7;            // row pair 0..1
    const int l  = t & 127;           // lane group; pixels w0 = 4l..4l+3
    const size_t rb0 = (size_t)(row0 + 2 * rp) * ROWLEN;
    const size_t rb1 = rb0 + ROWLEN;

    // ---- load 12 flats of both rows, pack half2 (lo=row0, hi=row1) ----
    {
        const int q = sq(7 + l);                 // chunk of e = 28+4l
        if (MASKP) {
            const unsigned int* mw = (const unsigned int*)srcv;
            const size_t wr0 = (size_t)(row0 + 2 * rp) * 48;
            const int pos = 12 * l, w0i = pos >> 5, sh = pos & 31;
            const u64 winA = ((u64)mw[wr0 + w0i + 1] << 32) | mw[wr0 + w0i];
            const u64 winB = ((u64)mw[wr0 + 48 + w0i + 1] << 32) | mw[wr0 + 48 + w0i];
            const unsigned bA = (unsigned)(winA >> sh) & 0xFFFu;
            const unsigned bB = (unsigned)(winB >> sh) & 0xFFFu;
            const __half hz = __float2half_rn(0.f), ho = __float2half_rn(1.f);
            #pragma unroll
            for (int c = 0; c < 3; ++c) {
                union { __half2 h2[4]; uint4 u; } o;
                #pragma unroll
                for (int i = 0; i < 4; ++i) {
                    const int k = 3 * i + c;
                    o.h2[i] = __halves2half2((bA >> k) & 1 ? ho : hz,
                                             (bB >> k) & 1 ? ho : hz);
                }
                *(uint4*)&pl[(rp * 3 + c) * PSTR + 4 * q] = o.u;
            }
        } else {
            float f0[12], f1[12];
            const float* sfa = (const float*)srcv + rb0 + 12 * l;
            const float* sfb = (const float*)srcv + rb1 + 12 * l;
            *(nt4*)&f0[0] = __builtin_nontemporal_load((const nt4*)(sfa));
            *(nt4*)&f0[4] = __builtin_nontemporal_load((const nt4*)(sfa + 4));
            *(nt4*)&f0[8] = __builtin_nontemporal_load((const nt4*)(sfa + 8));
            *(nt4*)&f1[0] = __builtin_nontemporal_load((const nt4*)(sfb));
            *(nt4*)&f1[4] = __builtin_nontemporal_load((const nt4*)(sfb + 4));
            *(nt4*)&f1[8] = __builtin_nontemporal_load((const nt4*)(sfb + 8));
            union { __half h[12]; uint2 u2[3]; } pa, pb2;
            #pragma unroll
            for (int k = 0; k < 12; ++k) {
                pa.h[k]  = __float2half_rn(f0[k]);
                pb2.h[k] = __float2half_rn(f1[k]);
            }
            uint2* ipa = (uint2*)(imgh + rb0 + 12 * l);
            uint2* ipb = (uint2*)(imgh + rb1 + 12 * l);
            ipa[0] = pa.u2[0];  ipa[1] = pa.u2[1];  ipa[2] = pa.u2[2];
            ipb[0] = pb2.u2[0]; ipb[1] = pb2.u2[1]; ipb[2] = pb2.u2[2];
            #pragma unroll
            for (int c = 0; c < 3; ++c) {
                union { __half2 h2[4]; uint4 u; } o;
                #pragma unroll
                for (int i = 0; i < 4; ++i)
                    o.h2[i] = __halves2half2(pa.h[3 * i + c], pb2.h[3 * i + c]);
                *(uint4*)&pl[(rp * 3 + c) * PSTR + 4 * q] = o.u;
            }
        }
    }
    __syncthreads();

    // ---- reflect halos (np.pad 'reflect'): 6 planes x 50 elements ----
    #pragma unroll
    for (int it = 0; it < 2; ++it) {
        const int item = t + it * 256;
        if (item < 300) {
            const int p = item / 50, k = item % 50;
            int ed, es;
            if (k < 25) { const int j = k + 1;  ed = 28 - j;  es = 28 + j; }
            else        { const int j = k - 24; ed = 539 + j; es = 539 - j; }
            __half2* pb = &pl[p * PSTR];
            pb[4 * sq(ed >> 2) + (ed & 3)] = pb[4 * sq(es >> 2) + (es & 3)];
        }
    }
    __syncthreads();

    // ---- compute: acc2[c][a] = channel c, pixel w0+a, both rows ----
    __half2 acc2[3][4];
    const __half2 z2 = __float2half2_rn(0.f);
    #pragma unroll
    for (int c = 0; c < 3; ++c)
        #pragma unroll
        for (int a = 0; a < 4; ++a) acc2[c][a] = z2;

    #pragma unroll
    for (int c = 0; c < 3; ++c) {
        const __half2* pb = &pl[(rp * 3 + c) * PSTR];
        #pragma unroll
        for (int v = 0; v < 15; ++v) {
            union { uint4 u; __half2 h2[4]; } v4;
            v4.u = *(const uint4*)&pb[4 * sq(l + v)];
            #pragma unroll
            for (int mm = 0; mm < 4; ++mm) {
                const __half2 val = v4.h2[mm];
                #pragma unroll
                for (int a = 0; a < 4; ++a) {
                    const int jj = 4 * v + mm - a - 3;   // tap, compile-time
                    if (jj >= 0 && jj < KK)
                        acc2[c][a] = __hfma2(gw2[jj], val, acc2[c][a]);
                }
            }
        }
    }

    // ---- store: per row, 12 consecutive fp16 flats = 3 coalesced uint2 ----
    {
        union { __half h[12]; uint2 u2[3]; } pk;
        #pragma unroll
        for (int a = 0; a < 4; ++a)
            #pragma unroll
            for (int c = 0; c < 3; ++c) pk.h[3 * a + c] = __low2half(acc2[c][a]);
        uint2* dp = (uint2*)(dst + rb0 + 12 * l);
        dp[0] = pk.u2[0]; dp[1] = pk.u2[1]; dp[2] = pk.u2[2];
    }
    {
        union { __half h[12]; uint2 u2[3]; } pk;
        #pragma unroll
        for (int a = 0; a < 4; ++a)
            #pragma unroll
            for (int c = 0; c < 3; ++c) pk.h[3 * a + c] = __high2half(acc2[c][a]);
        uint2* dp = (uint2*)(dst + rb1 + 12 * l);
        dp[0] = pk.u2[0]; dp[1] = pk.u2[1]; dp[2] = pk.u2[2];
    }
}

// ---------------- shared v-pass geometry ------------------------------------
#define HC 128
#define VROWS 178    // HC + 2*RR
#define HSTR 72      // halfs per row

// ---------------- P2: v-blur tbufA -> bit-packed mask -----------------------
// Tile fp16 in LDS; thread = 8 cols x 4 rows; 816 hfma2 (proven guard).
// Epilogue: res = imgh - blur; 8 bits -> ONE byte store per row per thread.
__global__ __launch_bounds__(256) void k_vmask(const __half* __restrict__ src,
                                               const __half* __restrict__ imgh,
                                               unsigned char* __restrict__ maskp,
                                               const __half2* __restrict__ g2src) {
    __shared__ __align__(16) __half tile[VROWS * HSTR];
    const int t  = threadIdx.x;
    const int cg = t & 7;
    const int rg = t >> 3;
    const int bid = blockIdx.x;
    const int wcB = bid % 24;
    const int hB  = (bid / 24) & 3;
    const int b   = bid / 96;
    const int wc0 = wcB * 64;
    const int h0  = hB * HC;

    __half2 gw2[KK];
    #pragma unroll
    for (int i = 0; i < KK; ++i) gw2[i] = g2src[i];

    const size_t imgbase = (size_t)b * HH * ROWLEN;

    #pragma unroll
    for (int i = 0; i < 6; ++i) {
        const int m = t + 256 * i;
        if (m < VROWS * 8) {
            const int r = m >> 3, cc = m & 7;
            int hs = h0 - RR + r;
            hs = hs < 0 ? -hs : hs;
            hs = hs > 511 ? 1022 - hs : hs;
            *(uint4*)&tile[r * HSTR + 8 * cc] =
                *(const uint4*)&src[imgbase + (size_t)hs * ROWLEN + wc0 + 8 * cc];
        }
    }
    __syncthreads();

    __half2 acc[4][4];
    const __half2 z2 = __float2half2_rn(0.f);
    #pragma unroll
    for (int a = 0; a < 4; ++a)
        #pragma unroll
        for (int p = 0; p < 4; ++p) acc[a][p] = z2;

    const __half* base = &tile[(rg * 4) * HSTR + 8 * cg];
    #pragma unroll
    for (int jj = 0; jj < 54; ++jj) {
        const uint4 raw = *(const uint4*)(base + jj * HSTR);
        union { uint4 u; __half2 h2[4]; } v; v.u = raw;
        #pragma unroll
        for (int a = 0; a < 4; ++a) {
            const int tap = jj - a;
            if (tap >= 0 && tap < KK) {
                acc[a][0] = __hfma2(gw2[tap], v.h2[0], acc[a][0]);
                acc[a][1] = __hfma2(gw2[tap], v.h2[1], acc[a][1]);
                acc[a][2] = __hfma2(gw2[tap], v.h2[2], acc[a][2]);
                acc[a][3] = __hfma2(gw2[tap], v.h2[3], acc[a][3]);
            }
        }
    }

    #pragma unroll
    for (int a = 0; a < 4; ++a) {
        const int hh = h0 + rg * 4 + a;
        const size_t idx = imgbase + (size_t)hh * ROWLEN + wc0 + 8 * cg;
        union { uint4 u; __half2 h2[4]; } xl;
        xl.u = *(const uint4*)&imgh[idx];
        unsigned int byte = 0;
        #pragma unroll
        for (int p = 0; p < 4; ++p) {
            const float2 xf = __half22float2(xl.h2[p]);
            const float2 bf = __half22float2(acc[a][p]);
            if (fabsf(xf.x - bf.x) * 255.0f > 10.0f) byte |= 1u << (2 * p);
            if (fabsf(xf.y - bf.y) * 255.0f > 10.0f) byte |= 1u << (2 * p + 1);
        }
        maskp[((size_t)b * HH + hh) * 192 + (wc0 >> 3) + cg] = (unsigned char)byte;
    }
}

// ---------------- P4: dual v-conv (blur + soft-mask) + final blend ----------
// Two fp16 tiles (51.3 KB LDS). Conv loops sequential (proven structure x2).
// sharp computed inline from imgh+blur; out f32 via nontemporal stores.
__global__ __launch_bounds__(256) void k_vfinal(const __half* __restrict__ srcA,
                                                const __half* __restrict__ srcB,
                                                const __half* __restrict__ imgh,
                                                float* __restrict__ outp,
                                                const __half2* __restrict__ g2src) {
    __shared__ __align__(16) __half tileA[VROWS * HSTR];
    __shared__ __align__(16) __half tileB[VROWS * HSTR];
    const int t  = threadIdx.x;
    const int cg = t & 7;
    const int rg = t >> 3;
    const int bid = blockIdx.x;
    const int wcB = bid % 24;
    const int hB  = (bid / 24) & 3;
    const int b   = bid / 96;
    const int wc0 = wcB * 64;
    const int h0  = hB * HC;

    __half2 gw2[KK];
    #pragma unroll
    for (int i = 0; i < KK; ++i) gw2[i] = g2src[i];

    const size_t imgbase = (size_t)b * HH * ROWLEN;

    #pragma unroll
    for (int i = 0; i < 6; ++i) {
        const int m = t + 256 * i;
        if (m < VROWS * 8) {
            const int r = m >> 3, cc = m & 7;
            int hs = h0 - RR + r;
            hs = hs < 0 ? -hs : hs;
            hs = hs > 511 ? 1022 - hs : hs;
            const size_t ga = imgbase + (size_t)hs * ROWLEN + wc0 + 8 * cc;
            *(uint4*)&tileA[r * HSTR + 8 * cc] = *(const uint4*)&srcA[ga];
            *(uint4*)&tileB[r * HSTR + 8 * cc] = *(const uint4*)&srcB[ga];
        }
    }
    __syncthreads();

    const __half2 z2 = __float2half2_rn(0.f);
    __half2 accB[4][4], accS[4][4];
    #pragma unroll
    for (int a = 0; a < 4; ++a)
        #pragma unroll
        for (int p = 0; p < 4; ++p) { accB[a][p] = z2; accS[a][p] = z2; }

    const __half* baseA = &tileA[(rg * 4) * HSTR + 8 * cg];
    #pragma unroll
    for (int jj = 0; jj < 54; ++jj) {
        union { uint4 u; __half2 h2[4]; } v;
        v.u = *(const uint4*)(baseA + jj * HSTR);
        #pragma unroll
        for (int a = 0; a < 4; ++a) {
            const int tap = jj - a;
            if (tap >= 0 && tap < KK) {
                accB[a][0] = __hfma2(gw2[tap], v.h2[0], accB[a][0]);
                accB[a][1] = __hfma2(gw2[tap], v.h2[1], accB[a][1]);
                accB[a][2] = __hfma2(gw2[tap], v.h2[2], accB[a][2]);
                accB[a][3] = __hfma2(gw2[tap], v.h2[3], accB[a][3]);
            }
        }
    }
    const __half* baseB = &tileB[(rg * 4) * HSTR + 8 * cg];
    #pragma unroll
    for (int jj = 0; jj < 54; ++jj) {
        union { uint4 u; __half2 h2[4]; } v;
        v.u = *(const uint4*)(baseB + jj * HSTR);
        #pragma unroll
        for (int a = 0; a < 4; ++a) {
            const int tap = jj - a;
            if (tap >= 0 && tap < KK) {
                accS[a][0] = __hfma2(gw2[tap], v.h2[0], accS[a][0]);
                accS[a][1] = __hfma2(gw2[tap], v.h2[1], accS[a][1]);
                accS[a][2] = __hfma2(gw2[tap], v.h2[2], accS[a][2]);
                accS[a][3] = __hfma2(gw2[tap], v.h2[3], accS[a][3]);
            }
        }
    }

    #pragma unroll
    for (int a = 0; a < 4; ++a) {
        const int hh = h0 + rg * 4 + a;
        const size_t idx = imgbase + (size_t)hh * ROWLEN + wc0 + 8 * cg;
        union { uint4 u; __half2 h2[4]; } xl;
        xl.u = *(const uint4*)&imgh[idx];
        float ov[8];
        #pragma unroll
        for (int p = 0; p < 4; ++p) {
            const float2 xf = __half22float2(xl.h2[p]);
            const float2 bf = __half22float2(accB[a][p]);
            const float2 sf = __half22float2(accS[a][p]);
            const float sh0 = fminf(fmaxf(xf.x + 0.5f * (xf.x - bf.x), 0.f), 1.f);
            const float sh1 = fminf(fmaxf(xf.y + 0.5f * (xf.y - bf.y), 0.f), 1.f);
            ov[2*p]   = xf.x + sf.x * (sh0 - xf.x);
            ov[2*p+1] = xf.y + sf.y * (sh1 - xf.y);
        }
        nt4 o0, o1;
        o0.x = ov[0]; o0.y = ov[1]; o0.z = ov[2]; o0.w = ov[3];
        o1.x = ov[4]; o1.y = ov[5]; o1.z = ov[6]; o1.w = ov[7];
        __builtin_nontemporal_store(o0, (nt4*)&outp[idx]);
        __builtin_nontemporal_store(o1, (nt4*)&outp[idx + 4]);
    }
}

// ---------------------------------------------------------------------------
extern "C" void kernel_launch(void* const* d_in, const int* in_sizes, int n_in,
                              void* d_out, int out_size, void* d_ws, size_t ws_size,
                              hipStream_t stream) {
    (void)in_sizes; (void)n_in; (void)out_size; (void)ws_size;
    const float* img = (const float*)d_in[0];
    const float* k2d = (const float*)d_in[1];
    float* out = (float*)d_out;

    const size_t NPX = (size_t)BB * HH * ROWLEN;   // 12.58M flats
    char* ws = (char*)d_ws;
    float* g = (float*)ws;                          // 51 f32 (256B slot)
    __half2* g2 = (__half2*)(ws + 256);             // 51 half2 (256B slot)
    __half* tbufA = (__half*)(ws + 512);                         // 25.2 MB
    __half* tbufB = (__half*)(ws + 512 + NPX * 2);               // 25.2 MB
    __half* imgh  = (__half*)(ws + 512 + NPX * 4);               // 25.2 MB
    unsigned char* maskp = (unsigned char*)(ws + 512 + NPX * 6); // 1.57 MB + pad

    const int nhblk = BB * HH / 4;        // 2048
    const int nvblk = BB * 4 * 24;        // 1536

    k_weights<<<1, 64, 0, stream>>>(k2d, g, g2);
    // P1: H-blur img -> tbufA (fp16); also emit imgh
    k_hconv<false><<<nhblk, 256, 0, stream>>>((const void*)img, tbufA, imgh, g2);
    // P2: V-blur tbufA -> blur (regs); bit-packed mask out
    k_vmask<<<nvblk, 256, 0, stream>>>(tbufA, imgh, maskp, g2);
    // P3: H-blur maskp -> tbufB (fp16)
    k_hconv<true><<<nhblk, 256, 0, stream>>>((const void*)maskp, tbufB, imgh, g2);
    // P4: dual V-blur (tbufA -> blur, tbufB -> soft mask) + blend -> d_out
    k_vfinal<<<nvblk, 256, 0, stream>>>(tbufA, tbufB, imgh, out, g2);
}

// Round 17
// 104.706 us; speedup vs baseline: 1.0428x; 1.0428x over previous
//
#include <hip/hip_runtime.h>
#include <hip/hip_fp16.h>

#define BB 16
#define HH 512
#define ROWLEN 1536   // W*C
#define KK 51
#define RR 25
typedef unsigned long long u64;
typedef float nt4 __attribute__((ext_vector_type(4)));   // native vec for NT ld/st

// chunk-level XOR swizzle (involution): spreads strided chunk patterns over
// all 8 bank groups; bijective (only low 3 bits change).
__device__ __forceinline__ int sq(int q) { return q ^ ((q >> 3) & 7); }

// ---------------- K0: reduce 2D kernel to 1D weights (g[i] = row sum) -------
__global__ void k_weights(const float* __restrict__ k2d, float* __restrict__ g,
                          __half2* __restrict__ g2) {
    int i = threadIdx.x;
    if (i < KK) {
        float s = 0.f;
        for (int j = 0; j < KK; ++j) s += k2d[i * KK + j];
        g[i] = s;
        g2[i] = __float2half2_rn(s);
    }
}

// ---------------- H-pass: 51-tap conv along w, row-pair packed fp16 ---------
// 4 rows/block, 256 threads = 2 row-pairs x 128 lanes. half2 lanes carry the
// two rows of a pair. Plane = (rowpair, channel), e = w+28, chunk-swizzled.
// Thread: 4 px x 3 ch x 2 rows = 24 outputs, 612 hfma2, guard compile-time.
// MASKP=false: src = f32 img (nontemporal), also emits imgh.
// MASKP=true:  src = bit-packed mask (1 bit/px flat, 48 words/row).
#define PSTR 576     // half2 per plane = 144 chunks (multiple of 8)
template<bool MASKP>
__global__ __launch_bounds__(256, 4) void k_hconv(const void* __restrict__ srcv,
                                                  __half* __restrict__ dst,
                                                  __half* __restrict__ imgh,
                                                  const __half2* __restrict__ g2src) {
    __shared__ __align__(16) __half2 pl[6 * PSTR];
    const int t = threadIdx.x;
    const int row0 = blockIdx.x * 4;             // first of 4 rows (b*512+h)

    __half2 gw2[KK];
    #pragma unroll
    for (int i = 0; i < KK; ++i) gw2[i] = g2src[i];   // uniform

    const int rp = t >> 7;            // row pair 0..1
    const int l  = t & 127;           // lane group; pixels w0 = 4l..4l+3
    const size_t rb0 = (size_t)(row0 + 2 * rp) * ROWLEN;
    const size_t rb1 = rb0 + ROWLEN;

    // ---- load 12 flats of both rows, pack half2 (lo=row0, hi=row1) ----
    {
        const int q = sq(7 + l);                 // chunk of e = 28+4l
        if (MASKP) {
            const unsigned int* mw = (const unsigned int*)srcv;
            const size_t wr0 = (size_t)(row0 + 2 * rp) * 48;
            const int pos = 12 * l, w0i = pos >> 5, sh = pos & 31;
            const u64 winA = ((u64)mw[wr0 + w0i + 1] << 32) | mw[wr0 + w0i];
            const u64 winB = ((u64)mw[wr0 + 48 + w0i + 1] << 32) | mw[wr0 + 48 + w0i];
            const unsigned bA = (unsigned)(winA >> sh) & 0xFFFu;
            const unsigned bB = (unsigned)(winB >> sh) & 0xFFFu;
            const __half hz = __float2half_rn(0.f), ho = __float2half_rn(1.f);
            #pragma unroll
            for (int c = 0; c < 3; ++c) {
                union { __half2 h2[4]; uint4 u; } o;
                #pragma unroll
                for (int i = 0; i < 4; ++i) {
                    const int k = 3 * i + c;
                    o.h2[i] = __halves2half2((bA >> k) & 1 ? ho : hz,
                                             (bB >> k) & 1 ? ho : hz);
                }
                *(uint4*)&pl[(rp * 3 + c) * PSTR + 4 * q] = o.u;
            }
        } else {
            float f0[12], f1[12];
            const float* sfa = (const float*)srcv + rb0 + 12 * l;
            const float* sfb = (const float*)srcv + rb1 + 12 * l;
            *(nt4*)&f0[0] = __builtin_nontemporal_load((const nt4*)(sfa));
            *(nt4*)&f0[4] = __builtin_nontemporal_load((const nt4*)(sfa + 4));
            *(nt4*)&f0[8] = __builtin_nontemporal_load((const nt4*)(sfa + 8));
            *(nt4*)&f1[0] = __builtin_nontemporal_load((const nt4*)(sfb));
            *(nt4*)&f1[4] = __builtin_nontemporal_load((const nt4*)(sfb + 4));
            *(nt4*)&f1[8] = __builtin_nontemporal_load((const nt4*)(sfb + 8));
            union { __half h[12]; uint2 u2[3]; } pa, pb2;
            #pragma unroll
            for (int k = 0; k < 12; ++k) {
                pa.h[k]  = __float2half_rn(f0[k]);
                pb2.h[k] = __float2half_rn(f1[k]);
            }
            uint2* ipa = (uint2*)(imgh + rb0 + 12 * l);
            uint2* ipb = (uint2*)(imgh + rb1 + 12 * l);
            ipa[0] = pa.u2[0];  ipa[1] = pa.u2[1];  ipa[2] = pa.u2[2];
            ipb[0] = pb2.u2[0]; ipb[1] = pb2.u2[1]; ipb[2] = pb2.u2[2];
            #pragma unroll
            for (int c = 0; c < 3; ++c) {
                union { __half2 h2[4]; uint4 u; } o;
                #pragma unroll
                for (int i = 0; i < 4; ++i)
                    o.h2[i] = __halves2half2(pa.h[3 * i + c], pb2.h[3 * i + c]);
                *(uint4*)&pl[(rp * 3 + c) * PSTR + 4 * q] = o.u;
            }
        }
    }
    __syncthreads();

    // ---- reflect halos (np.pad 'reflect'): 6 planes x 50 elements ----
    #pragma unroll
    for (int it = 0; it < 2; ++it) {
        const int item = t + it * 256;
        if (item < 300) {
            const int p = item / 50, k = item % 50;
            int ed, es;
            if (k < 25) { const int j = k + 1;  ed = 28 - j;  es = 28 + j; }
            else        { const int j = k - 24; ed = 539 + j; es = 539 - j; }
            __half2* pb = &pl[p * PSTR];
            pb[4 * sq(ed >> 2) + (ed & 3)] = pb[4 * sq(es >> 2) + (es & 3)];
        }
    }
    __syncthreads();

    // ---- compute: acc2[c][a] = channel c, pixel w0+a, both rows ----
    __half2 acc2[3][4];
    const __half2 z2 = __float2half2_rn(0.f);
    #pragma unroll
    for (int c = 0; c < 3; ++c)
        #pragma unroll
        for (int a = 0; a < 4; ++a) acc2[c][a] = z2;

    #pragma unroll
    for (int c = 0; c < 3; ++c) {
        const __half2* pb = &pl[(rp * 3 + c) * PSTR];
        #pragma unroll
        for (int v = 0; v < 15; ++v) {
            union { uint4 u; __half2 h2[4]; } v4;
            v4.u = *(const uint4*)&pb[4 * sq(l + v)];
            #pragma unroll
            for (int mm = 0; mm < 4; ++mm) {
                const __half2 val = v4.h2[mm];
                #pragma unroll
                for (int a = 0; a < 4; ++a) {
                    const int jj = 4 * v + mm - a - 3;   // tap, compile-time
                    if (jj >= 0 && jj < KK)
                        acc2[c][a] = __hfma2(gw2[jj], val, acc2[c][a]);
                }
            }
        }
    }

    // ---- store: per row, 12 consecutive fp16 flats = 3 coalesced uint2 ----
    {
        union { __half h[12]; uint2 u2[3]; } pk;
        #pragma unroll
        for (int a = 0; a < 4; ++a)
            #pragma unroll
            for (int c = 0; c < 3; ++c) pk.h[3 * a + c] = __low2half(acc2[c][a]);
        uint2* dp = (uint2*)(dst + rb0 + 12 * l);
        dp[0] = pk.u2[0]; dp[1] = pk.u2[1]; dp[2] = pk.u2[2];
    }
    {
        union { __half h[12]; uint2 u2[3]; } pk;
        #pragma unroll
        for (int a = 0; a < 4; ++a)
            #pragma unroll
            for (int c = 0; c < 3; ++c) pk.h[3 * a + c] = __high2half(acc2[c][a]);
        uint2* dp = (uint2*)(dst + rb1 + 12 * l);
        dp[0] = pk.u2[0]; dp[1] = pk.u2[1]; dp[2] = pk.u2[2];
    }
}

// ---------------- V-pass: 51-tap conv along h, packed fp16 ------------------
// Tile: 64 cols x 128 out rows (+50 halo), fp16 in LDS, row stride 72 halfs.
// 256 threads = 8 col-groups (8 cols = 4 half2) x 32 row-groups (4 rows).
// 816 hfma2/thread, guard compile-time (proven R13/R14 structure).
// MODE 0: blur(regs) -> sharp16 (fp16) + BIT-PACKED mask (1 byte/thread/row).
// MODE 1: soft-mask -> blend imgh/sharp16 -> outp (f32, NT stores).
#define HC 128
#define VROWS 178    // HC + 2*RR
#define HSTR 72      // halfs per row

template<int MODE>
__global__ __launch_bounds__(256) void k_vconv(const __half* __restrict__ src,
                                               const __half* __restrict__ imgh,
                                               __half* __restrict__ sharp16,
                                               float* __restrict__ outp,
                                               unsigned char* __restrict__ maskp,
                                               const __half2* __restrict__ g2src) {
    __shared__ __align__(16) __half tile[VROWS * HSTR];
    const int t  = threadIdx.x;
    const int cg = t & 7;                // col group: cols 8*cg..8*cg+7
    const int rg = t >> 3;               // row group: rows rg*4..rg*4+3
    const int bid = blockIdx.x;
    const int wcB = bid % 24;
    const int hB  = (bid / 24) & 3;
    const int b   = bid / 96;
    const int wc0 = wcB * 64;
    const int h0  = hB * HC;

    __half2 gw2[KK];
    #pragma unroll
    for (int i = 0; i < KK; ++i) gw2[i] = g2src[i];

    const size_t imgbase = (size_t)b * HH * ROWLEN;

    // ---- load tile (178 rows x 8 chunks of 8 halfs) with reflect on h ----
    #pragma unroll
    for (int i = 0; i < 6; ++i) {
        const int m = t + 256 * i;
        if (m < VROWS * 8) {
            const int r = m >> 3, cc = m & 7;
            int hs = h0 - RR + r;
            hs = hs < 0 ? -hs : hs;
            hs = hs > 511 ? 1022 - hs : hs;
            *(uint4*)&tile[r * HSTR + 8 * cc] =
                *(const uint4*)&src[imgbase + (size_t)hs * ROWLEN + wc0 + 8 * cc];
        }
    }
    __syncthreads();

    __half2 acc[4][4];
    const __half2 z2 = __float2half2_rn(0.f);
    #pragma unroll
    for (int a = 0; a < 4; ++a)
        #pragma unroll
        for (int p = 0; p < 4; ++p) acc[a][p] = z2;

    const __half* base = &tile[(rg * 4) * HSTR + 8 * cg];
    #pragma unroll
    for (int jj = 0; jj < 54; ++jj) {
        const uint4 raw = *(const uint4*)(base + jj * HSTR);
        union { uint4 u; __half2 h2[4]; } v; v.u = raw;
        #pragma unroll
        for (int a = 0; a < 4; ++a) {
            const int tap = jj - a;                  // compile-time guard
            if (tap >= 0 && tap < KK) {
                acc[a][0] = __hfma2(gw2[tap], v.h2[0], acc[a][0]);
                acc[a][1] = __hfma2(gw2[tap], v.h2[1], acc[a][1]);
                acc[a][2] = __hfma2(gw2[tap], v.h2[2], acc[a][2]);
                acc[a][3] = __hfma2(gw2[tap], v.h2[3], acc[a][3]);
            }
        }
    }

    // ---- fused epilogue (f32 math, 8 cols per row) ----
    #pragma unroll
    for (int a = 0; a < 4; ++a) {
        const int hh = h0 + rg * 4 + a;
        const size_t idx = imgbase + (size_t)hh * ROWLEN + wc0 + 8 * cg;
        union { uint4 u; __half2 h2[4]; } xl;
        xl.u = *(const uint4*)&imgh[idx];
        float xv[8], bv[8];
        #pragma unroll
        for (int p = 0; p < 4; ++p) {
            const float2 xf = __half22float2(xl.h2[p]);
            const float2 bf = __half22float2(acc[a][p]);
            xv[2*p] = xf.x; xv[2*p+1] = xf.y;
            bv[2*p] = bf.x; bv[2*p+1] = bf.y;
        }
        if (MODE == 0) {
            union { __half h[8]; uint4 u; } sh;
            unsigned int byte = 0;
            #pragma unroll
            for (int m = 0; m < 8; ++m) {
                const float x = xv[m];
                const float res = x - bv[m];
                sh.h[m] = __float2half_rn(fminf(fmaxf(x + 0.5f * res, 0.f), 1.f));
                if (fabsf(res) * 255.0f > 10.0f) byte |= 1u << m;
            }
            *(uint4*)&sharp16[idx] = sh.u;
            maskp[((size_t)b * HH + hh) * 192 + (wc0 >> 3) + cg] = (unsigned char)byte;
        } else {
            union { uint4 u; __half2 h2[4]; } sl;
            sl.u = *(const uint4*)&sharp16[idx];
            float ov[8];
            #pragma unroll
            for (int p = 0; p < 4; ++p) {
                const float2 sf = __half22float2(sl.h2[p]);
                ov[2*p]   = xv[2*p]   + bv[2*p]   * (sf.x - xv[2*p]);
                ov[2*p+1] = xv[2*p+1] + bv[2*p+1] * (sf.y - xv[2*p+1]);
            }
            nt4 o0, o1;
            o0.x = ov[0]; o0.y = ov[1]; o0.z = ov[2]; o0.w = ov[3];
            o1.x = ov[4]; o1.y = ov[5]; o1.z = ov[6]; o1.w = ov[7];
            __builtin_nontemporal_store(o0, (nt4*)&outp[idx]);
            __builtin_nontemporal_store(o1, (nt4*)&outp[idx + 4]);
        }
    }
}

// ---------------------------------------------------------------------------
extern "C" void kernel_launch(void* const* d_in, const int* in_sizes, int n_in,
                              void* d_out, int out_size, void* d_ws, size_t ws_size,
                              hipStream_t stream) {
    (void)in_sizes; (void)n_in; (void)out_size; (void)ws_size;
    const float* img = (const float*)d_in[0];
    const float* k2d = (const float*)d_in[1];
    float* out = (float*)d_out;

    const size_t NPX = (size_t)BB * HH * ROWLEN;   // 12.58M flats
    char* ws = (char*)d_ws;
    float* g = (float*)ws;                          // 51 f32 (256B slot)
    __half2* g2 = (__half2*)(ws + 256);             // 51 half2 (256B slot)
    __half* tbuf = (__half*)(ws + 512);                          // 25.2 MB
    __half* sharp16 = (__half*)(ws + 512 + NPX * 2);             // 25.2 MB
    __half* imgh    = (__half*)(ws + 512 + NPX * 4);             // 25.2 MB
    unsigned char* maskp = (unsigned char*)(ws + 512 + NPX * 6); // 1.57 MB

    const int nhblk = BB * HH / 4;        // 2048
    const int nvblk = BB * 4 * 24;        // 1536

    k_weights<<<1, 64, 0, stream>>>(k2d, g, g2);
    // P1: H-blur img -> tbuf (fp16); also emit imgh (fp16 copy of img)
    k_hconv<false><<<nhblk, 256, 0, stream>>>((const void*)img, tbuf, imgh, g2);
    // P2: V-blur tbuf -> blur (regs); sharp16 + bit-packed mask out
    k_vconv<0><<<nvblk, 256, 0, stream>>>(tbuf, imgh, sharp16, out, maskp, g2);
    // P3: H-blur maskp -> tbuf (fp16)
    k_hconv<true><<<nhblk, 256, 0, stream>>>((const void*)maskp, tbuf, imgh, g2);
    // P4: V-blur tbuf -> soft mask; blend imgh/sharp16 -> d_out (f32, NT)
    k_vconv<1><<<nvblk, 256, 0, stream>>>(tbuf, imgh, sharp16, out, maskp, g2);
}

// Round 18
// 99.525 us; speedup vs baseline: 1.0971x; 1.0521x over previous
//
#include <hip/hip_runtime.h>
#include <hip/hip_fp16.h>

#define BB 16
#define HH 512
#define ROWLEN 1536   // W*C
#define KK 51
#define RR 25
typedef unsigned long long u64;
typedef float nt4 __attribute__((ext_vector_type(4)));   // native vec for NT st

// chunk-level XOR swizzle (involution): spreads strided chunk patterns over
// all 8 bank groups; bijective (only low 3 bits change).
__device__ __forceinline__ int sq(int q) { return q ^ ((q >> 3) & 7); }

// ---------------- K0: reduce 2D kernel to 1D weights (g[i] = row sum) -------
__global__ void k_weights(const float* __restrict__ k2d, float* __restrict__ g,
                          __half2* __restrict__ g2) {
    int i = threadIdx.x;
    if (i < KK) {
        float s = 0.f;
        for (int j = 0; j < KK; ++j) s += k2d[i * KK + j];
        g[i] = s;
        g2[i] = __float2half2_rn(s);
    }
}

// ---------------- H-pass: 51-tap conv along w, row-pair packed fp16 ---------
// 4 rows/block, 256 threads = 2 row-pairs x 128 lanes. half2 lanes carry the
// two rows of a pair. Plane = (rowpair, channel), e = w+28, chunk-swizzled.
// Thread: 4 px x 3 ch x 2 rows = 24 outputs, 612 hfma2, guard compile-time.
// MASKP=false: src = f32 img (regular loads -- img must stay L3-resident
// across graph replays; NT loads cost ~8us/replay, measured R17).
// MASKP=true:  src = bit-packed mask (1 bit/px flat, 48 words/row).
#define PSTR 576     // half2 per plane = 144 chunks (multiple of 8)
template<bool MASKP>
__global__ __launch_bounds__(256, 4) void k_hconv(const void* __restrict__ srcv,
                                                  __half* __restrict__ dst,
                                                  __half* __restrict__ imgh,
                                                  const __half2* __restrict__ g2src) {
    __shared__ __align__(16) __half2 pl[6 * PSTR];
    const int t = threadIdx.x;
    const int row0 = blockIdx.x * 4;             // first of 4 rows (b*512+h)

    __half2 gw2[KK];
    #pragma unroll
    for (int i = 0; i < KK; ++i) gw2[i] = g2src[i];   // uniform

    const int rp = t >> 7;            // row pair 0..1
    const int l  = t & 127;           // lane group; pixels w0 = 4l..4l+3
    const size_t rb0 = (size_t)(row0 + 2 * rp) * ROWLEN;
    const size_t rb1 = rb0 + ROWLEN;

    // ---- load 12 flats of both rows, pack half2 (lo=row0, hi=row1) ----
    {
        const int q = sq(7 + l);                 // chunk of e = 28+4l
        if (MASKP) {
            const unsigned int* mw = (const unsigned int*)srcv;
            const size_t wr0 = (size_t)(row0 + 2 * rp) * 48;
            const int pos = 12 * l, w0i = pos >> 5, sh = pos & 31;
            const u64 winA = ((u64)mw[wr0 + w0i + 1] << 32) | mw[wr0 + w0i];
            const u64 winB = ((u64)mw[wr0 + 48 + w0i + 1] << 32) | mw[wr0 + 48 + w0i];
            const unsigned bA = (unsigned)(winA >> sh) & 0xFFFu;
            const unsigned bB = (unsigned)(winB >> sh) & 0xFFFu;
            const __half hz = __float2half_rn(0.f), ho = __float2half_rn(1.f);
            #pragma unroll
            for (int c = 0; c < 3; ++c) {
                union { __half2 h2[4]; uint4 u; } o;
                #pragma unroll
                for (int i = 0; i < 4; ++i) {
                    const int k = 3 * i + c;
                    o.h2[i] = __halves2half2((bA >> k) & 1 ? ho : hz,
                                             (bB >> k) & 1 ? ho : hz);
                }
                *(uint4*)&pl[(rp * 3 + c) * PSTR + 4 * q] = o.u;
            }
        } else {
            float f0[12], f1[12];
            const float* sfa = (const float*)srcv + rb0 + 12 * l;
            const float* sfb = (const float*)srcv + rb1 + 12 * l;
            *(float4*)&f0[0] = *(const float4*)(sfa);
            *(float4*)&f0[4] = *(const float4*)(sfa + 4);
            *(float4*)&f0[8] = *(const float4*)(sfa + 8);
            *(float4*)&f1[0] = *(const float4*)(sfb);
            *(float4*)&f1[4] = *(const float4*)(sfb + 4);
            *(float4*)&f1[8] = *(const float4*)(sfb + 8);
            union { __half h[12]; uint2 u2[3]; } pa, pb2;
            #pragma unroll
            for (int k = 0; k < 12; ++k) {
                pa.h[k]  = __float2half_rn(f0[k]);
                pb2.h[k] = __float2half_rn(f1[k]);
            }
            uint2* ipa = (uint2*)(imgh + rb0 + 12 * l);
            uint2* ipb = (uint2*)(imgh + rb1 + 12 * l);
            ipa[0] = pa.u2[0];  ipa[1] = pa.u2[1];  ipa[2] = pa.u2[2];
            ipb[0] = pb2.u2[0]; ipb[1] = pb2.u2[1]; ipb[2] = pb2.u2[2];
            #pragma unroll
            for (int c = 0; c < 3; ++c) {
                union { __half2 h2[4]; uint4 u; } o;
                #pragma unroll
                for (int i = 0; i < 4; ++i)
                    o.h2[i] = __halves2half2(pa.h[3 * i + c], pb2.h[3 * i + c]);
                *(uint4*)&pl[(rp * 3 + c) * PSTR + 4 * q] = o.u;
            }
        }
    }
    __syncthreads();

    // ---- reflect halos (np.pad 'reflect'): 6 planes x 50 elements ----
    #pragma unroll
    for (int it = 0; it < 2; ++it) {
        const int item = t + it * 256;
        if (item < 300) {
            const int p = item / 50, k = item % 50;
            int ed, es;
            if (k < 25) { const int j = k + 1;  ed = 28 - j;  es = 28 + j; }
            else        { const int j = k - 24; ed = 539 + j; es = 539 - j; }
            __half2* pb = &pl[p * PSTR];
            pb[4 * sq(ed >> 2) + (ed & 3)] = pb[4 * sq(es >> 2) + (es & 3)];
        }
    }
    __syncthreads();

    // ---- compute: acc2[c][a] = channel c, pixel w0+a, both rows ----
    __half2 acc2[3][4];
    const __half2 z2 = __float2half2_rn(0.f);
    #pragma unroll
    for (int c = 0; c < 3; ++c)
        #pragma unroll
        for (int a = 0; a < 4; ++a) acc2[c][a] = z2;

    #pragma unroll
    for (int c = 0; c < 3; ++c) {
        const __half2* pb = &pl[(rp * 3 + c) * PSTR];
        #pragma unroll
        for (int v = 0; v < 15; ++v) {
            union { uint4 u; __half2 h2[4]; } v4;
            v4.u = *(const uint4*)&pb[4 * sq(l + v)];
            #pragma unroll
            for (int mm = 0; mm < 4; ++mm) {
                const __half2 val = v4.h2[mm];
                #pragma unroll
                for (int a = 0; a < 4; ++a) {
                    const int jj = 4 * v + mm - a - 3;   // tap, compile-time
                    if (jj >= 0 && jj < KK)
                        acc2[c][a] = __hfma2(gw2[jj], val, acc2[c][a]);
                }
            }
        }
    }

    // ---- store: per row, 12 consecutive fp16 flats = 3 coalesced uint2 ----
    {
        union { __half h[12]; uint2 u2[3]; } pk;
        #pragma unroll
        for (int a = 0; a < 4; ++a)
            #pragma unroll
            for (int c = 0; c < 3; ++c) pk.h[3 * a + c] = __low2half(acc2[c][a]);
        uint2* dp = (uint2*)(dst + rb0 + 12 * l);
        dp[0] = pk.u2[0]; dp[1] = pk.u2[1]; dp[2] = pk.u2[2];
    }
    {
        union { __half h[12]; uint2 u2[3]; } pk;
        #pragma unroll
        for (int a = 0; a < 4; ++a)
            #pragma unroll
            for (int c = 0; c < 3; ++c) pk.h[3 * a + c] = __high2half(acc2[c][a]);
        uint2* dp = (uint2*)(dst + rb1 + 12 * l);
        dp[0] = pk.u2[0]; dp[1] = pk.u2[1]; dp[2] = pk.u2[2];
    }
}

// ---------------- V-pass: 51-tap conv along h, packed fp16 ------------------
// Tile: 64 cols x 128 out rows (+50 halo), fp16 in LDS, row stride 72 halfs.
// 256 threads = 8 col-groups (8 cols = 4 half2) x 32 row-groups (4 rows).
// 816 hfma2/thread, guard compile-time (proven R13/R14 structure).
// MODE 0: blur(regs) -> sharp16 (fp16) + BIT-PACKED mask (1 byte/thread/row).
// MODE 1: soft-mask -> blend imgh/sharp16 -> outp (f32, NT stores).
#define HC 128
#define VROWS 178    // HC + 2*RR
#define HSTR 72      // halfs per row

template<int MODE>
__global__ __launch_bounds__(256) void k_vconv(const __half* __restrict__ src,
                                               const __half* __restrict__ imgh,
                                               __half* __restrict__ sharp16,
                                               float* __restrict__ outp,
                                               unsigned char* __restrict__ maskp,
                                               const __half2* __restrict__ g2src) {
    __shared__ __align__(16) __half tile[VROWS * HSTR];
    const int t  = threadIdx.x;
    const int cg = t & 7;                // col group: cols 8*cg..8*cg+7
    const int rg = t >> 3;               // row group: rows rg*4..rg*4+3
    const int bid = blockIdx.x;
    const int wcB = bid % 24;
    const int hB  = (bid / 24) & 3;
    const int b   = bid / 96;
    const int wc0 = wcB * 64;
    const int h0  = hB * HC;

    __half2 gw2[KK];
    #pragma unroll
    for (int i = 0; i < KK; ++i) gw2[i] = g2src[i];

    const size_t imgbase = (size_t)b * HH * ROWLEN;

    // ---- load tile (178 rows x 8 chunks of 8 halfs) with reflect on h ----
    #pragma unroll
    for (int i = 0; i < 6; ++i) {
        const int m = t + 256 * i;
        if (m < VROWS * 8) {
            const int r = m >> 3, cc = m & 7;
            int hs = h0 - RR + r;
            hs = hs < 0 ? -hs : hs;
            hs = hs > 511 ? 1022 - hs : hs;
            *(uint4*)&tile[r * HSTR + 8 * cc] =
                *(const uint4*)&src[imgbase + (size_t)hs * ROWLEN + wc0 + 8 * cc];
        }
    }
    __syncthreads();

    __half2 acc[4][4];
    const __half2 z2 = __float2half2_rn(0.f);
    #pragma unroll
    for (int a = 0; a < 4; ++a)
        #pragma unroll
        for (int p = 0; p < 4; ++p) acc[a][p] = z2;

    const __half* base = &tile[(rg * 4) * HSTR + 8 * cg];
    #pragma unroll
    for (int jj = 0; jj < 54; ++jj) {
        const uint4 raw = *(const uint4*)(base + jj * HSTR);
        union { uint4 u; __half2 h2[4]; } v; v.u = raw;
        #pragma unroll
        for (int a = 0; a < 4; ++a) {
            const int tap = jj - a;                  // compile-time guard
            if (tap >= 0 && tap < KK) {
                acc[a][0] = __hfma2(gw2[tap], v.h2[0], acc[a][0]);
                acc[a][1] = __hfma2(gw2[tap], v.h2[1], acc[a][1]);
                acc[a][2] = __hfma2(gw2[tap], v.h2[2], acc[a][2]);
                acc[a][3] = __hfma2(gw2[tap], v.h2[3], acc[a][3]);
            }
        }
    }

    // ---- fused epilogue (f32 math, 8 cols per row) ----
    #pragma unroll
    for (int a = 0; a < 4; ++a) {
        const int hh = h0 + rg * 4 + a;
        const size_t idx = imgbase + (size_t)hh * ROWLEN + wc0 + 8 * cg;
        union { uint4 u; __half2 h2[4]; } xl;
        xl.u = *(const uint4*)&imgh[idx];
        float xv[8], bv[8];
        #pragma unroll
        for (int p = 0; p < 4; ++p) {
            const float2 xf = __half22float2(xl.h2[p]);
            const float2 bf = __half22float2(acc[a][p]);
            xv[2*p] = xf.x; xv[2*p+1] = xf.y;
            bv[2*p] = bf.x; bv[2*p+1] = bf.y;
        }
        if (MODE == 0) {
            union { __half h[8]; uint4 u; } sh;
            unsigned int byte = 0;
            #pragma unroll
            for (int m = 0; m < 8; ++m) {
                const float x = xv[m];
                const float res = x - bv[m];
                sh.h[m] = __float2half_rn(fminf(fmaxf(x + 0.5f * res, 0.f), 1.f));
                if (fabsf(res) * 255.0f > 10.0f) byte |= 1u << m;
            }
            *(uint4*)&sharp16[idx] = sh.u;
            maskp[((size_t)b * HH + hh) * 192 + (wc0 >> 3) + cg] = (unsigned char)byte;
        } else {
            union { uint4 u; __half2 h2[4]; } sl;
            sl.u = *(const uint4*)&sharp16[idx];
            float ov[8];
            #pragma unroll
            for (int p = 0; p < 4; ++p) {
                const float2 sf = __half22float2(sl.h2[p]);
                ov[2*p]   = xv[2*p]   + bv[2*p]   * (sf.x - xv[2*p]);
                ov[2*p+1] = xv[2*p+1] + bv[2*p+1] * (sf.y - xv[2*p+1]);
            }
            nt4 o0, o1;
            o0.x = ov[0]; o0.y = ov[1]; o0.z = ov[2]; o0.w = ov[3];
            o1.x = ov[4]; o1.y = ov[5]; o1.z = ov[6]; o1.w = ov[7];
            __builtin_nontemporal_store(o0, (nt4*)&outp[idx]);
            __builtin_nontemporal_store(o1, (nt4*)&outp[idx + 4]);
        }
    }
}

// ---------------------------------------------------------------------------
extern "C" void kernel_launch(void* const* d_in, const int* in_sizes, int n_in,
                              void* d_out, int out_size, void* d_ws, size_t ws_size,
                              hipStream_t stream) {
    (void)in_sizes; (void)n_in; (void)out_size; (void)ws_size;
    const float* img = (const float*)d_in[0];
    const float* k2d = (const float*)d_in[1];
    float* out = (float*)d_out;

    const size_t NPX = (size_t)BB * HH * ROWLEN;   // 12.58M flats
    char* ws = (char*)d_ws;
    float* g = (float*)ws;                          // 51 f32 (256B slot)
    __half2* g2 = (__half2*)(ws + 256);             // 51 half2 (256B slot)
    __half* tbuf = (__half*)(ws + 512);                          // 25.2 MB
    __half* sharp16 = (__half*)(ws + 512 + NPX * 2);             // 25.2 MB
    __half* imgh    = (__half*)(ws + 512 + NPX * 4);             // 25.2 MB
    unsigned char* maskp = (unsigned char*)(ws + 512 + NPX * 6); // 1.57 MB

    const int nhblk = BB * HH / 4;        // 2048
    const int nvblk = BB * 4 * 24;        // 1536

    k_weights<<<1, 64, 0, stream>>>(k2d, g, g2);
    // P1: H-blur img -> tbuf (fp16); also emit imgh (fp16 copy of img)
    k_hconv<false><<<nhblk, 256, 0, stream>>>((const void*)img, tbuf, imgh, g2);
    // P2: V-blur tbuf -> blur (regs); sharp16 + bit-packed mask out
    k_vconv<0><<<nvblk, 256, 0, stream>>>(tbuf, imgh, sharp16, out, maskp, g2);
    // P3: H-blur maskp -> tbuf (fp16)
    k_hconv<true><<<nhblk, 256, 0, stream>>>((const void*)maskp, tbuf, imgh, g2);
    // P4: V-blur tbuf -> soft mask; blend imgh/sharp16 -> d_out (f32, NT)
    k_vconv<1><<<nvblk, 256, 0, stream>>>(tbuf, imgh, sharp16, out, maskp, g2);
}

// Round 19
// 98.825 us; speedup vs baseline: 1.1049x; 1.0071x over previous
//
#include <hip/hip_runtime.h>
#include <hip/hip_fp16.h>

#define BB 16
#define HH 512
#define ROWLEN 1536   // W*C
#define KK 51
#define RR 25
typedef unsigned long long u64;

// chunk-level XOR swizzle (involution): spreads strided chunk patterns over
// all 8 bank groups; bijective (only low 3 bits change).
__device__ __forceinline__ int sq(int q) { return q ^ ((q >> 3) & 7); }

// ---------------- K0: reduce 2D kernel to 1D weights (g[i] = row sum) -------
__global__ void k_weights(const float* __restrict__ k2d, float* __restrict__ g,
                          __half2* __restrict__ g2) {
    int i = threadIdx.x;
    if (i < KK) {
        float s = 0.f;
        for (int j = 0; j < KK; ++j) s += k2d[i * KK + j];
        g[i] = s;
        g2[i] = __float2half2_rn(s);
    }
}

// ---------------- H-pass: 51-tap conv along w, row-pair packed fp16 ---------
// 4 rows/block, 256 threads = 2 row-pairs x 128 lanes. half2 lanes carry the
// two rows of a pair. Plane = (rowpair, channel), e = w+28, chunk-swizzled.
// Thread: 4 px x 3 ch x 2 rows = 24 outputs, 612 hfma2, guard compile-time.
// MASKP=false: src = f32 img (regular loads -- img must stay L3-resident
// across graph replays; NT loads cost ~5us/replay, measured R17/R18).
// MASKP=true:  src = bit-packed mask (1 bit/px flat, 48 words/row).
#define PSTR 576     // half2 per plane = 144 chunks (multiple of 8)
template<bool MASKP>
__global__ __launch_bounds__(256, 4) void k_hconv(const void* __restrict__ srcv,
                                                  __half* __restrict__ dst,
                                                  __half* __restrict__ imgh,
                                                  const __half2* __restrict__ g2src) {
    __shared__ __align__(16) __half2 pl[6 * PSTR];
    const int t = threadIdx.x;
    const int row0 = blockIdx.x * 4;             // first of 4 rows (b*512+h)

    __half2 gw2[KK];
    #pragma unroll
    for (int i = 0; i < KK; ++i) gw2[i] = g2src[i];   // uniform

    const int rp = t >> 7;            // row pair 0..1
    const int l  = t & 127;           // lane group; pixels w0 = 4l..4l+3
    const size_t rb0 = (size_t)(row0 + 2 * rp) * ROWLEN;
    const size_t rb1 = rb0 + ROWLEN;

    // ---- load 12 flats of both rows, pack half2 (lo=row0, hi=row1) ----
    {
        const int q = sq(7 + l);                 // chunk of e = 28+4l
        if (MASKP) {
            const unsigned int* mw = (const unsigned int*)srcv;
            const size_t wr0 = (size_t)(row0 + 2 * rp) * 48;
            const int pos = 12 * l, w0i = pos >> 5, sh = pos & 31;
            const u64 winA = ((u64)mw[wr0 + w0i + 1] << 32) | mw[wr0 + w0i];
            const u64 winB = ((u64)mw[wr0 + 48 + w0i + 1] << 32) | mw[wr0 + 48 + w0i];
            const unsigned bA = (unsigned)(winA >> sh) & 0xFFFu;
            const unsigned bB = (unsigned)(winB >> sh) & 0xFFFu;
            const __half hz = __float2half_rn(0.f), ho = __float2half_rn(1.f);
            #pragma unroll
            for (int c = 0; c < 3; ++c) {
                union { __half2 h2[4]; uint4 u; } o;
                #pragma unroll
                for (int i = 0; i < 4; ++i) {
                    const int k = 3 * i + c;
                    o.h2[i] = __halves2half2((bA >> k) & 1 ? ho : hz,
                                             (bB >> k) & 1 ? ho : hz);
                }
                *(uint4*)&pl[(rp * 3 + c) * PSTR + 4 * q] = o.u;
            }
        } else {
            float f0[12], f1[12];
            const float* sfa = (const float*)srcv + rb0 + 12 * l;
            const float* sfb = (const float*)srcv + rb1 + 12 * l;
            *(float4*)&f0[0] = *(const float4*)(sfa);
            *(float4*)&f0[4] = *(const float4*)(sfa + 4);
            *(float4*)&f0[8] = *(const float4*)(sfa + 8);
            *(float4*)&f1[0] = *(const float4*)(sfb);
            *(float4*)&f1[4] = *(const float4*)(sfb + 4);
            *(float4*)&f1[8] = *(const float4*)(sfb + 8);
            union { __half h[12]; uint2 u2[3]; } pa, pb2;
            #pragma unroll
            for (int k = 0; k < 12; ++k) {
                pa.h[k]  = __float2half_rn(f0[k]);
                pb2.h[k] = __float2half_rn(f1[k]);
            }
            uint2* ipa = (uint2*)(imgh + rb0 + 12 * l);
            uint2* ipb = (uint2*)(imgh + rb1 + 12 * l);
            ipa[0] = pa.u2[0];  ipa[1] = pa.u2[1];  ipa[2] = pa.u2[2];
            ipb[0] = pb2.u2[0]; ipb[1] = pb2.u2[1]; ipb[2] = pb2.u2[2];
            #pragma unroll
            for (int c = 0; c < 3; ++c) {
                union { __half2 h2[4]; uint4 u; } o;
                #pragma unroll
                for (int i = 0; i < 4; ++i)
                    o.h2[i] = __halves2half2(pa.h[3 * i + c], pb2.h[3 * i + c]);
                *(uint4*)&pl[(rp * 3 + c) * PSTR + 4 * q] = o.u;
            }
        }
    }
    __syncthreads();

    // ---- reflect halos (np.pad 'reflect'): 6 planes x 50 elements ----
    #pragma unroll
    for (int it = 0; it < 2; ++it) {
        const int item = t + it * 256;
        if (item < 300) {
            const int p = item / 50, k = item % 50;
            int ed, es;
            if (k < 25) { const int j = k + 1;  ed = 28 - j;  es = 28 + j; }
            else        { const int j = k - 24; ed = 539 + j; es = 539 - j; }
            __half2* pb = &pl[p * PSTR];
            pb[4 * sq(ed >> 2) + (ed & 3)] = pb[4 * sq(es >> 2) + (es & 3)];
        }
    }
    __syncthreads();

    // ---- compute: acc2[c][a] = channel c, pixel w0+a, both rows ----
    __half2 acc2[3][4];
    const __half2 z2 = __float2half2_rn(0.f);
    #pragma unroll
    for (int c = 0; c < 3; ++c)
        #pragma unroll
        for (int a = 0; a < 4; ++a) acc2[c][a] = z2;

    #pragma unroll
    for (int c = 0; c < 3; ++c) {
        const __half2* pb = &pl[(rp * 3 + c) * PSTR];
        #pragma unroll
        for (int v = 0; v < 15; ++v) {
            union { uint4 u; __half2 h2[4]; } v4;
            v4.u = *(const uint4*)&pb[4 * sq(l + v)];
            #pragma unroll
            for (int mm = 0; mm < 4; ++mm) {
                const __half2 val = v4.h2[mm];
                #pragma unroll
                for (int a = 0; a < 4; ++a) {
                    const int jj = 4 * v + mm - a - 3;   // tap, compile-time
                    if (jj >= 0 && jj < KK)
                        acc2[c][a] = __hfma2(gw2[jj], val, acc2[c][a]);
                }
            }
        }
    }

    // ---- store: per row, 12 consecutive fp16 flats = 3 coalesced uint2 ----
    {
        union { __half h[12]; uint2 u2[3]; } pk;
        #pragma unroll
        for (int a = 0; a < 4; ++a)
            #pragma unroll
            for (int c = 0; c < 3; ++c) pk.h[3 * a + c] = __low2half(acc2[c][a]);
        uint2* dp = (uint2*)(dst + rb0 + 12 * l);
        dp[0] = pk.u2[0]; dp[1] = pk.u2[1]; dp[2] = pk.u2[2];
    }
    {
        union { __half h[12]; uint2 u2[3]; } pk;
        #pragma unroll
        for (int a = 0; a < 4; ++a)
            #pragma unroll
            for (int c = 0; c < 3; ++c) pk.h[3 * a + c] = __high2half(acc2[c][a]);
        uint2* dp = (uint2*)(dst + rb1 + 12 * l);
        dp[0] = pk.u2[0]; dp[1] = pk.u2[1]; dp[2] = pk.u2[2];
    }
}

// ---------------- V-pass: 51-tap conv along h, packed fp16 ------------------
// Tile: 64 cols x 128 out rows (+50 halo), fp16 in LDS, row stride 72 halfs.
// 256 threads = 8 col-groups (8 cols = 4 half2) x 32 row-groups (4 rows).
// 816 hfma2/thread, guard compile-time (proven R13/R14 structure).
// MODE 0: blur(regs) -> sharp16 (fp16) + BIT-PACKED mask (1 byte/thread/row).
// MODE 1: soft-mask -> blend imgh/sharp16 -> outp (f32, regular stores --
// L3-absorbed, lazy writeback; NT stores cost ~3.5us in-kernel, measured R18).
#define HC 128
#define VROWS 178    // HC + 2*RR
#define HSTR 72      // halfs per row

template<int MODE>
__global__ __launch_bounds__(256) void k_vconv(const __half* __restrict__ src,
                                               const __half* __restrict__ imgh,
                                               __half* __restrict__ sharp16,
                                               float* __restrict__ outp,
                                               unsigned char* __restrict__ maskp,
                                               const __half2* __restrict__ g2src) {
    __shared__ __align__(16) __half tile[VROWS * HSTR];
    const int t  = threadIdx.x;
    const int cg = t & 7;                // col group: cols 8*cg..8*cg+7
    const int rg = t >> 3;               // row group: rows rg*4..rg*4+3
    const int bid = blockIdx.x;
    const int wcB = bid % 24;
    const int hB  = (bid / 24) & 3;
    const int b   = bid / 96;
    const int wc0 = wcB * 64;
    const int h0  = hB * HC;

    __half2 gw2[KK];
    #pragma unroll
    for (int i = 0; i < KK; ++i) gw2[i] = g2src[i];

    const size_t imgbase = (size_t)b * HH * ROWLEN;

    // ---- load tile (178 rows x 8 chunks of 8 halfs) with reflect on h ----
    #pragma unroll
    for (int i = 0; i < 6; ++i) {
        const int m = t + 256 * i;
        if (m < VROWS * 8) {
            const int r = m >> 3, cc = m & 7;
            int hs = h0 - RR + r;
            hs = hs < 0 ? -hs : hs;
            hs = hs > 511 ? 1022 - hs : hs;
            *(uint4*)&tile[r * HSTR + 8 * cc] =
                *(const uint4*)&src[imgbase + (size_t)hs * ROWLEN + wc0 + 8 * cc];
        }
    }
    __syncthreads();

    __half2 acc[4][4];
    const __half2 z2 = __float2half2_rn(0.f);
    #pragma unroll
    for (int a = 0; a < 4; ++a)
        #pragma unroll
        for (int p = 0; p < 4; ++p) acc[a][p] = z2;

    const __half* base = &tile[(rg * 4) * HSTR + 8 * cg];
    #pragma unroll
    for (int jj = 0; jj < 54; ++jj) {
        const uint4 raw = *(const uint4*)(base + jj * HSTR);
        union { uint4 u; __half2 h2[4]; } v; v.u = raw;
        #pragma unroll
        for (int a = 0; a < 4; ++a) {
            const int tap = jj - a;                  // compile-time guard
            if (tap >= 0 && tap < KK) {
                acc[a][0] = __hfma2(gw2[tap], v.h2[0], acc[a][0]);
                acc[a][1] = __hfma2(gw2[tap], v.h2[1], acc[a][1]);
                acc[a][2] = __hfma2(gw2[tap], v.h2[2], acc[a][2]);
                acc[a][3] = __hfma2(gw2[tap], v.h2[3], acc[a][3]);
            }
        }
    }

    // ---- fused epilogue (f32 math, 8 cols per row) ----
    #pragma unroll
    for (int a = 0; a < 4; ++a) {
        const int hh = h0 + rg * 4 + a;
        const size_t idx = imgbase + (size_t)hh * ROWLEN + wc0 + 8 * cg;
        union { uint4 u; __half2 h2[4]; } xl;
        xl.u = *(const uint4*)&imgh[idx];
        float xv[8], bv[8];
        #pragma unroll
        for (int p = 0; p < 4; ++p) {
            const float2 xf = __half22float2(xl.h2[p]);
            const float2 bf = __half22float2(acc[a][p]);
            xv[2*p] = xf.x; xv[2*p+1] = xf.y;
            bv[2*p] = bf.x; bv[2*p+1] = bf.y;
        }
        if (MODE == 0) {
            union { __half h[8]; uint4 u; } sh;
            unsigned int byte = 0;
            #pragma unroll
            for (int m = 0; m < 8; ++m) {
                const float x = xv[m];
                const float res = x - bv[m];
                sh.h[m] = __float2half_rn(fminf(fmaxf(x + 0.5f * res, 0.f), 1.f));
                if (fabsf(res) * 255.0f > 10.0f) byte |= 1u << m;
            }
            *(uint4*)&sharp16[idx] = sh.u;
            maskp[((size_t)b * HH + hh) * 192 + (wc0 >> 3) + cg] = (unsigned char)byte;
        } else {
            union { uint4 u; __half2 h2[4]; } sl;
            sl.u = *(const uint4*)&sharp16[idx];
            float ov[8];
            #pragma unroll
            for (int p = 0; p < 4; ++p) {
                const float2 sf = __half22float2(sl.h2[p]);
                ov[2*p]   = xv[2*p]   + bv[2*p]   * (sf.x - xv[2*p]);
                ov[2*p+1] = xv[2*p+1] + bv[2*p+1] * (sf.y - xv[2*p+1]);
            }
            float4 o0, o1;
            o0.x = ov[0]; o0.y = ov[1]; o0.z = ov[2]; o0.w = ov[3];
            o1.x = ov[4]; o1.y = ov[5]; o1.z = ov[6]; o1.w = ov[7];
            *(float4*)&outp[idx]     = o0;
            *(float4*)&outp[idx + 4] = o1;
        }
    }
}

// ---------------------------------------------------------------------------
extern "C" void kernel_launch(void* const* d_in, const int* in_sizes, int n_in,
                              void* d_out, int out_size, void* d_ws, size_t ws_size,
                              hipStream_t stream) {
    (void)in_sizes; (void)n_in; (void)out_size; (void)ws_size;
    const float* img = (const float*)d_in[0];
    const float* k2d = (const float*)d_in[1];
    float* out = (float*)d_out;

    const size_t NPX = (size_t)BB * HH * ROWLEN;   // 12.58M flats
    char* ws = (char*)d_ws;
    float* g = (float*)ws;                          // 51 f32 (256B slot)
    __half2* g2 = (__half2*)(ws + 256);             // 51 half2 (256B slot)
    __half* tbuf = (__half*)(ws + 512);                          // 25.2 MB
    __half* sharp16 = (__half*)(ws + 512 + NPX * 2);             // 25.2 MB
    __half* imgh    = (__half*)(ws + 512 + NPX * 4);             // 25.2 MB
    unsigned char* maskp = (unsigned char*)(ws + 512 + NPX * 6); // 1.57 MB

    const int nhblk = BB * HH / 4;        // 2048
    const int nvblk = BB * 4 * 24;        // 1536

    k_weights<<<1, 64, 0, stream>>>(k2d, g, g2);
    // P1: H-blur img -> tbuf (fp16); also emit imgh (fp16 copy of img)
    k_hconv<false><<<nhblk, 256, 0, stream>>>((const void*)img, tbuf, imgh, g2);
    // P2: V-blur tbuf -> blur (regs); sharp16 + bit-packed mask out
    k_vconv<0><<<nvblk, 256, 0, stream>>>(tbuf, imgh, sharp16, out, maskp, g2);
    // P3: H-blur maskp -> tbuf (fp16)
    k_hconv<true><<<nhblk, 256, 0, stream>>>((const void*)maskp, tbuf, imgh, g2);
    // P4: V-blur tbuf -> soft mask; blend imgh/sharp16 -> d_out (f32)
    k_vconv<1><<<nvblk, 256, 0, stream>>>(tbuf, imgh, sharp16, out, maskp, g2);
}

// Round 20
// 95.622 us; speedup vs baseline: 1.1419x; 1.0335x over previous
//
#include <hip/hip_runtime.h>
#include <hip/hip_fp16.h>

#define BB 16
#define HH 512
#define ROWLEN 1536   // W*C
#define KK 51
#define RR 25

// chunk-level XOR swizzle (involution): spreads strided chunk patterns over
// all 8 bank groups; bijective (only low 3 bits change).
__device__ __forceinline__ int sq(int q) { return q ^ ((q >> 3) & 7); }

// ---------------- K0: reduce 2D kernel to 1D weights (g[i] = row sum) -------
__global__ void k_weights(const float* __restrict__ k2d, float* __restrict__ g,
                          __half2* __restrict__ g2) {
    int i = threadIdx.x;
    if (i < KK) {
        float s = 0.f;
        for (int j = 0; j < KK; ++j) s += k2d[i * KK + j];
        g[i] = s;
        g2[i] = __float2half2_rn(s);
    }
}

// ---------------- H-pass: 51-tap conv along w, row-pair packed fp16 ---------
// 4 rows/block, 256 threads = 2 row-pairs x 128 lanes. half2 lanes carry the
// two rows of a pair (independent convs, same taps -> no unaligned pair
// extraction). Plane = (rowpair, channel): 576 half2 elements, e = w+28,
// chunk-swizzled addr = plane*576 + 4*sq(e>>2) + (e&3) (half2 units: 4B each,
// bank math identical to proven f32 R8 skeleton). Thread owns 4 pixels x 3 ch
// x 2 rows = 24 outputs: 612 hfma2, guard compile-time. Store: 3 uint2 per
// row, coalesced. U8=false also emits imgh (fp16 copy of img, both rows).
#define PSTR 576     // half2 per plane = 144 chunks (multiple of 8)
template<bool U8>
__global__ __launch_bounds__(256, 4) void k_hconv(const void* __restrict__ srcv,
                                                  __half* __restrict__ dst,
                                                  __half* __restrict__ imgh,
                                                  const __half2* __restrict__ g2src) {
    __shared__ __align__(16) __half2 pl[6 * PSTR];
    const int t = threadIdx.x;
    const int row0 = blockIdx.x * 4;             // first of 4 rows (b*512+h)

    __half2 gw2[KK];
    #pragma unroll
    for (int i = 0; i < KK; ++i) gw2[i] = g2src[i];   // uniform

    const int rp = t >> 7;            // row pair 0..1
    const int l  = t & 127;           // lane group; pixels w0 = 4l..4l+3
    const size_t rb0 = (size_t)(row0 + 2 * rp) * ROWLEN;
    const size_t rb1 = rb0 + ROWLEN;

    // ---- load 12 flats of both rows, pack half2 (lo=row0, hi=row1) ----
    {
        float f0[12], f1[12];
        if (U8) {
            const unsigned char* sa = (const unsigned char*)srcv + rb0 + 12 * l;
            const unsigned char* sb = (const unsigned char*)srcv + rb1 + 12 * l;
            unsigned int wa[3], wb[3];
            wa[0] = *(const unsigned int*)(sa);
            wa[1] = *(const unsigned int*)(sa + 4);
            wa[2] = *(const unsigned int*)(sa + 8);
            wb[0] = *(const unsigned int*)(sb);
            wb[1] = *(const unsigned int*)(sb + 4);
            wb[2] = *(const unsigned int*)(sb + 8);
            #pragma unroll
            for (int k = 0; k < 12; ++k) {
                f0[k] = (float)((wa[k >> 2] >> ((k & 3) * 8)) & 0xffu);
                f1[k] = (float)((wb[k >> 2] >> ((k & 3) * 8)) & 0xffu);
            }
        } else {
            const float* sfa = (const float*)srcv + rb0 + 12 * l;
            const float* sfb = (const float*)srcv + rb1 + 12 * l;
            *(float4*)&f0[0] = *(const float4*)(sfa);
            *(float4*)&f0[4] = *(const float4*)(sfa + 4);
            *(float4*)&f0[8] = *(const float4*)(sfa + 8);
            *(float4*)&f1[0] = *(const float4*)(sfb);
            *(float4*)&f1[4] = *(const float4*)(sfb + 4);
            *(float4*)&f1[8] = *(const float4*)(sfb + 8);
        }
        union { __half h[12]; uint2 u2[3]; } pa, pb2;
        #pragma unroll
        for (int k = 0; k < 12; ++k) {
            pa.h[k]  = __float2half_rn(f0[k]);
            pb2.h[k] = __float2half_rn(f1[k]);
        }
        if (!U8) {
            uint2* ipa = (uint2*)(imgh + rb0 + 12 * l);
            uint2* ipb = (uint2*)(imgh + rb1 + 12 * l);
            ipa[0] = pa.u2[0];  ipa[1] = pa.u2[1];  ipa[2] = pa.u2[2];
            ipb[0] = pb2.u2[0]; ipb[1] = pb2.u2[1]; ipb[2] = pb2.u2[2];
        }
        const int q = sq(7 + l);                 // chunk of e = 28+4l
        #pragma unroll
        for (int c = 0; c < 3; ++c) {
            union { __half2 h2[4]; uint4 u; } o;
            #pragma unroll
            for (int i = 0; i < 4; ++i)
                o.h2[i] = __halves2half2(pa.h[3 * i + c], pb2.h[3 * i + c]);
            *(uint4*)&pl[(rp * 3 + c) * PSTR + 4 * q] = o.u;
        }
    }
    __syncthreads();

    // ---- reflect halos (np.pad 'reflect'): 6 planes x 50 elements ----
    #pragma unroll
    for (int it = 0; it < 2; ++it) {
        const int item = t + it * 256;
        if (item < 300) {
            const int p = item / 50, k = item % 50;
            int ed, es;
            if (k < 25) { const int j = k + 1;  ed = 28 - j;  es = 28 + j; }
            else        { const int j = k - 24; ed = 539 + j; es = 539 - j; }
            __half2* pb = &pl[p * PSTR];
            pb[4 * sq(ed >> 2) + (ed & 3)] = pb[4 * sq(es >> 2) + (es & 3)];
        }
    }
    __syncthreads();

    // ---- compute: acc2[c][a] = channel c, pixel w0+a, both rows ----
    __half2 acc2[3][4];
    const __half2 z2 = __float2half2_rn(0.f);
    #pragma unroll
    for (int c = 0; c < 3; ++c)
        #pragma unroll
        for (int a = 0; a < 4; ++a) acc2[c][a] = z2;

    #pragma unroll
    for (int c = 0; c < 3; ++c) {
        const __half2* pb = &pl[(rp * 3 + c) * PSTR];
        #pragma unroll
        for (int v = 0; v < 15; ++v) {
            union { uint4 u; __half2 h2[4]; } v4;
            v4.u = *(const uint4*)&pb[4 * sq(l + v)];
            #pragma unroll
            for (int mm = 0; mm < 4; ++mm) {
                const __half2 val = v4.h2[mm];
                #pragma unroll
                for (int a = 0; a < 4; ++a) {
                    const int jj = 4 * v + mm - a - 3;   // tap, compile-time
                    if (jj >= 0 && jj < KK)
                        acc2[c][a] = __hfma2(gw2[jj], val, acc2[c][a]);
                }
            }
        }
    }

    // ---- store: per row, 12 consecutive fp16 flats = 3 coalesced uint2 ----
    {
        union { __half h[12]; uint2 u2[3]; } pk;
        #pragma unroll
        for (int a = 0; a < 4; ++a)
            #pragma unroll
            for (int c = 0; c < 3; ++c) pk.h[3 * a + c] = __low2half(acc2[c][a]);
        uint2* dp = (uint2*)(dst + rb0 + 12 * l);
        dp[0] = pk.u2[0]; dp[1] = pk.u2[1]; dp[2] = pk.u2[2];
    }
    {
        union { __half h[12]; uint2 u2[3]; } pk;
        #pragma unroll
        for (int a = 0; a < 4; ++a)
            #pragma unroll
            for (int c = 0; c < 3; ++c) pk.h[3 * a + c] = __high2half(acc2[c][a]);
        uint2* dp = (uint2*)(dst + rb1 + 12 * l);
        dp[0] = pk.u2[0]; dp[1] = pk.u2[1]; dp[2] = pk.u2[2];
    }
}

// ---------------- V-pass: 51-tap conv along h, packed fp16 ------------------
// Tile: 64 cols x 128 out rows (+50 halo), fp16 in LDS, row stride 72 halfs.
// 256 threads = 8 col-groups (8 cols = 4 half2, one b128/row) x 32 row-groups
// (4 rows). 816 v_pk_fma_f16/thread, guard compile-time.
// MODE 0: blur(regs) -> sharp16 (fp16) + mask8 (byte/px). MODE 1: soft-mask
// -> blend imgh/sharp16 -> outp (f32, regular stores).
#define HC 128
#define VROWS 178    // HC + 2*RR
#define HSTR 72      // halfs per row

template<int MODE>
__global__ __launch_bounds__(256) void k_vconv(const __half* __restrict__ src,
                                               const __half* __restrict__ imgh,
                                               __half* __restrict__ sharp16,
                                               float* __restrict__ outp,
                                               unsigned char* __restrict__ mask8,
                                               const __half2* __restrict__ g2src) {
    __shared__ __align__(16) __half tile[VROWS * HSTR];
    const int t  = threadIdx.x;
    const int cg = t & 7;                // col group: cols 8*cg..8*cg+7
    const int rg = t >> 3;               // row group: rows rg*4..rg*4+3
    const int bid = blockIdx.x;
    const int wcB = bid % 24;
    const int hB  = (bid / 24) & 3;
    const int b   = bid / 96;
    const int wc0 = wcB * 64;
    const int h0  = hB * HC;

    __half2 gw2[KK];
    #pragma unroll
    for (int i = 0; i < KK; ++i) gw2[i] = g2src[i];

    const size_t imgbase = (size_t)b * HH * ROWLEN;

    // ---- load tile (178 rows x 8 chunks of 8 halfs) with reflect on h ----
    #pragma unroll
    for (int i = 0; i < 6; ++i) {
        const int m = t + 256 * i;
        if (m < VROWS * 8) {
            const int r = m >> 3, cc = m & 7;
            int hs = h0 - RR + r;
            hs = hs < 0 ? -hs : hs;
            hs = hs > 511 ? 1022 - hs : hs;
            *(uint4*)&tile[r * HSTR + 8 * cc] =
                *(const uint4*)&src[imgbase + (size_t)hs * ROWLEN + wc0 + 8 * cc];
        }
    }
    __syncthreads();

    __half2 acc[4][4];
    const __half2 z2 = __float2half2_rn(0.f);
    #pragma unroll
    for (int a = 0; a < 4; ++a)
        #pragma unroll
        for (int p = 0; p < 4; ++p) acc[a][p] = z2;

    const __half* base = &tile[(rg * 4) * HSTR + 8 * cg];
    #pragma unroll
    for (int jj = 0; jj < 54; ++jj) {
        const uint4 raw = *(const uint4*)(base + jj * HSTR);
        union { uint4 u; __half2 h2[4]; } v; v.u = raw;
        #pragma unroll
        for (int a = 0; a < 4; ++a) {
            const int tap = jj - a;                  // compile-time guard
            if (tap >= 0 && tap < KK) {
                acc[a][0] = __hfma2(gw2[tap], v.h2[0], acc[a][0]);
                acc[a][1] = __hfma2(gw2[tap], v.h2[1], acc[a][1]);
                acc[a][2] = __hfma2(gw2[tap], v.h2[2], acc[a][2]);
                acc[a][3] = __hfma2(gw2[tap], v.h2[3], acc[a][3]);
            }
        }
    }

    // ---- fused epilogue (f32 math, 8 cols per row) ----
    #pragma unroll
    for (int a = 0; a < 4; ++a) {
        const int hh = h0 + rg * 4 + a;
        const size_t idx = imgbase + (size_t)hh * ROWLEN + wc0 + 8 * cg;
        union { uint4 u; __half2 h2[4]; } xl;
        xl.u = *(const uint4*)&imgh[idx];
        float xv[8], bv[8];
        #pragma unroll
        for (int p = 0; p < 4; ++p) {
            const float2 xf = __half22float2(xl.h2[p]);
            const float2 bf = __half22float2(acc[a][p]);
            xv[2*p] = xf.x; xv[2*p+1] = xf.y;
            bv[2*p] = bf.x; bv[2*p+1] = bf.y;
        }
        if (MODE == 0) {
            union { __half h[8]; uint4 u; } sh;
            unsigned int mwlo = 0, mwhi = 0;
            #pragma unroll
            for (int m = 0; m < 8; ++m) {
                const float x = xv[m];
                const float res = x - bv[m];
                sh.h[m] = __float2half_rn(fminf(fmaxf(x + 0.5f * res, 0.f), 1.f));
                const unsigned int bit = (fabsf(res) * 255.0f > 10.0f) ? 1u : 0u;
                if (m < 4) mwlo |= bit << (8 * m); else mwhi |= bit << (8 * (m - 4));
            }
            *(uint4*)&sharp16[idx] = sh.u;
            uint2 mo; mo.x = mwlo; mo.y = mwhi;
            *(uint2*)&mask8[idx] = mo;
        } else {
            union { uint4 u; __half2 h2[4]; } sl;
            sl.u = *(const uint4*)&sharp16[idx];
            float ov[8];
            #pragma unroll
            for (int p = 0; p < 4; ++p) {
                const float2 sf = __half22float2(sl.h2[p]);
                ov[2*p]   = xv[2*p]   + bv[2*p]   * (sf.x - xv[2*p]);
                ov[2*p+1] = xv[2*p+1] + bv[2*p+1] * (sf.y - xv[2*p+1]);
            }
            float4 o0, o1;
            o0.x = ov[0]; o0.y = ov[1]; o0.z = ov[2]; o0.w = ov[3];
            o1.x = ov[4]; o1.y = ov[5]; o1.z = ov[6]; o1.w = ov[7];
            *(float4*)&outp[idx]     = o0;
            *(float4*)&outp[idx + 4] = o1;
        }
    }
}

// ---------------------------------------------------------------------------
extern "C" void kernel_launch(void* const* d_in, const int* in_sizes, int n_in,
                              void* d_out, int out_size, void* d_ws, size_t ws_size,
                              hipStream_t stream) {
    (void)in_sizes; (void)n_in; (void)out_size; (void)ws_size;
    const float* img = (const float*)d_in[0];
    const float* k2d = (const float*)d_in[1];
    float* out = (float*)d_out;

    const size_t NPX = (size_t)BB * HH * ROWLEN;   // 12.58M flats
    char* ws = (char*)d_ws;
    float* g = (float*)ws;                          // 51 f32 (256B slot)
    __half2* g2 = (__half2*)(ws + 256);             // 51 half2 (256B slot)
    __half* tbuf = (__half*)(ws + 512);             // 25.2 MB
    unsigned char* mask8 = (unsigned char*)(ws + 512 + NPX * 2);      // 12.6 MB
    __half* sharp16 = (__half*)(ws + 512 + NPX * 2 + NPX);            // 25.2 MB
    __half* imgh    = (__half*)(ws + 512 + NPX * 2 + NPX + NPX * 2);  // 25.2 MB

    const int nhblk = BB * HH / 4;        // 2048
    const int nvblk = BB * 4 * 24;        // 1536

    k_weights<<<1, 64, 0, stream>>>(k2d, g, g2);
    // P1: H-blur img -> tbuf (fp16); also emit imgh (fp16 copy of img)
    k_hconv<false><<<nhblk, 256, 0, stream>>>((const void*)img, tbuf, imgh, g2);
    // P2: V-blur tbuf -> blur (regs); sharp16 + mask8 out (reads imgh)
    k_vconv<0><<<nvblk, 256, 0, stream>>>(tbuf, imgh, sharp16, out, mask8, g2);
    // P3: H-blur mask8 -> tbuf (fp16)
    k_hconv<true><<<nhblk, 256, 0, stream>>>((const void*)mask8, tbuf, imgh, g2);
    // P4: V-blur tbuf -> soft mask; blend imgh/sharp16 -> d_out (f32)
    k_vconv<1><<<nvblk, 256, 0, stream>>>(tbuf, imgh, sharp16, out, mask8, g2);
}